// Round 17
// baseline (141.788 us; speedup 1.0000x reference)
//
#include <hip/hip_runtime.h>
#include <hip/hip_bf16.h>
#include <math.h>

// Problem constants (B=1)
#define S_LEN 2048
#define D_DIM 512
#define H_NUM 8
#define HD    64
#define C_NUM 32
#define TOPK  5
#define SCALE 0.125f   // hd^-0.5
#define QCAP  1024     // fixed qlist capacity per (h,c); load is ~320
#define ABLK  4        // attn blocks per (h,c)  (R15-verified)

typedef __attribute__((ext_vector_type(8))) short bf16x8;   // 8 bf16 (4 VGPRs)
typedef __attribute__((ext_vector_type(4))) float f32x4;
typedef __attribute__((ext_vector_type(4))) unsigned short us4;

__device__ __forceinline__ unsigned short f2b(float f) {
    __hip_bfloat16 h = __float2bfloat16(f);
    unsigned short u;
    __builtin_memcpy(&u, &h, 2);
    return u;
}
__device__ __forceinline__ bf16x8 pack8(float4 a, float4 b) {
    bf16x8 r;
    r[0] = (short)f2b(a.x); r[1] = (short)f2b(a.y);
    r[2] = (short)f2b(a.z); r[3] = (short)f2b(a.w);
    r[4] = (short)f2b(b.x); r[5] = (short)f2b(b.y);
    r[6] = (short)f2b(b.z); r[7] = (short)f2b(b.w);
    return r;
}
__device__ __forceinline__ float b2f(unsigned short u) {
    __hip_bfloat16 h;
    __builtin_memcpy(&h, &u, 2);
    return __bfloat162float(h);
}
__device__ __forceinline__ us4 pack4(float4 v) {
    us4 o;
    o[0] = f2b(v.x); o[1] = f2b(v.y); o[2] = f2b(v.z); o[3] = f2b(v.w);
    return o;
}

// ---------------------------------------------------------------------------
// fp32 GEMM (R0-EXACT FMA CHAIN — 43us floor, CLOSED; routing-critical,
// k-ascending, do not touch). R16: epilogue also writes bf16 C copy from
// the same acc registers (feeds attention staging; bit-identical).
// Session lessons: R11 grid.sync costs 10s of us — separate dispatches.
// R14: at the <=2us/lever scale, bundle nothing.
// ---------------------------------------------------------------------------
#define BM 64
#define BN 64
#define BK 32

__device__ __forceinline__ void gemm_body(const float* __restrict__ A,
                                          const float* __restrict__ B,
                                          float* __restrict__ C,
                                          unsigned short* __restrict__ Cbf,
                                          int M, int N, int K,
                                          int bx, int by) {
    __shared__ float As[BK][BM + 4];
    __shared__ float Bs[BK][BN];

    const int t  = threadIdx.x;
    const int tx = t & 15;
    const int ty = t >> 4;
    const int m0 = by * BM;
    const int n0 = bx * BN;

    float4 acc0 = make_float4(0.f,0.f,0.f,0.f);
    float4 acc1 = make_float4(0.f,0.f,0.f,0.f);
    float4 acc2 = make_float4(0.f,0.f,0.f,0.f);
    float4 acc3 = make_float4(0.f,0.f,0.f,0.f);

    const int ar = t >> 3;
    const int ac = (t & 7) * 4;
    const int br = t >> 4;
    const int bc = (t & 15) * 4;

    float4 a0, a1, b0, b1;
    auto LD = [&](int k0) {
        a0 = *(const float4*)&A[(size_t)(m0 + ar)      * K + k0 + ac];
        a1 = *(const float4*)&A[(size_t)(m0 + ar + 32) * K + k0 + ac];
        b0 = *(const float4*)&B[(size_t)(k0 + br)      * N + n0 + bc];
        b1 = *(const float4*)&B[(size_t)(k0 + br + 16) * N + n0 + bc];
    };

    LD(0);
    for (int k0 = 0; k0 < K; k0 += BK) {
        __syncthreads();
        As[ac+0][ar]    = a0.x; As[ac+1][ar]    = a0.y; As[ac+2][ar]    = a0.z; As[ac+3][ar]    = a0.w;
        As[ac+0][ar+32] = a1.x; As[ac+1][ar+32] = a1.y; As[ac+2][ar+32] = a1.z; As[ac+3][ar+32] = a1.w;
        *(float4*)&Bs[br][bc]      = b0;
        *(float4*)&Bs[br + 16][bc] = b1;
        __syncthreads();

        if (k0 + BK < K) LD(k0 + BK);

        #pragma unroll
        for (int kk = 0; kk < BK; ++kk) {
            float4 a = *(const float4*)&As[kk][ty * 4];
            float4 b = *(const float4*)&Bs[kk][tx * 4];
            acc0.x += a.x*b.x; acc0.y += a.x*b.y; acc0.z += a.x*b.z; acc0.w += a.x*b.w;
            acc1.x += a.y*b.x; acc1.y += a.y*b.y; acc1.z += a.y*b.z; acc1.w += a.y*b.w;
            acc2.x += a.z*b.x; acc2.y += a.z*b.y; acc2.z += a.z*b.z; acc2.w += a.z*b.w;
            acc3.x += a.w*b.x; acc3.y += a.w*b.y; acc3.z += a.w*b.z; acc3.w += a.w*b.w;
        }
    }

    *(float4*)&C[(size_t)(m0 + ty*4 + 0) * N + n0 + tx*4] = acc0;
    *(float4*)&C[(size_t)(m0 + ty*4 + 1) * N + n0 + tx*4] = acc1;
    *(float4*)&C[(size_t)(m0 + ty*4 + 2) * N + n0 + tx*4] = acc2;
    *(float4*)&C[(size_t)(m0 + ty*4 + 3) * N + n0 + tx*4] = acc3;

    *(us4*)&Cbf[(size_t)(m0 + ty*4 + 0) * N + n0 + tx*4] = pack4(acc0);
    *(us4*)&Cbf[(size_t)(m0 + ty*4 + 1) * N + n0 + tx*4] = pack4(acc1);
    *(us4*)&Cbf[(size_t)(m0 + ty*4 + 2) * N + n0 + tx*4] = pack4(acc2);
    *(us4*)&Cbf[(size_t)(m0 + ty*4 + 3) * N + n0 + tx*4] = pack4(acc3);
}

// Q and K projections (z in {0,1}); fp32 math byte-identical to R0.
// Writes Qb/Kb (fp32, routing) + Qbf/Kbf (bf16, attention staging).
// Split xbf tail-pack (R15-verified).
__global__ __launch_bounds__(256) void gemm_qkv(const float* __restrict__ A,
                                                const float* __restrict__ Wq,
                                                const float* __restrict__ Wk,
                                                float* __restrict__ Qb,
                                                float* __restrict__ Kb,
                                                unsigned short* __restrict__ Qbf,
                                                unsigned short* __restrict__ Kbf,
                                                unsigned short* __restrict__ xbf) {
    const float* B = (blockIdx.z == 0) ? Wq : Wk;
    float*       C = (blockIdx.z == 0) ? Qb : Kb;
    unsigned short* Cbf = (blockIdx.z == 0) ? Qbf : Kbf;
    gemm_body(A, B, C, Cbf, S_LEN, D_DIM, D_DIM, blockIdx.x, blockIdx.y);
    {
        const int r0 = blockIdx.y * 64 + (int)blockIdx.z * 32;  // half-tile
        const int c0 = blockIdx.x * 64;
        for (int i = threadIdx.x; i < 32 * 16; i += 256) {
            int r = i >> 4, c4 = (i & 15) * 4;
            float4 v = *(const float4*)&A[(size_t)(r0 + r) * D_DIM + c0 + c4];
            *(us4*)&xbf[(size_t)(r0 + r) * D_DIM + c0 + c4] = pack4(v);
        }
    }
}

// ---------------------------------------------------------------------------
// bf16 MFMA GEMM — 64x32 tile (R13 win: 2 blocks/CU), dbuf one barrier per
// K-step (R10 win). Per-output MFMA chain statement-identical.
// ---------------------------------------------------------------------------
template <bool ABF16, bool CBF16>
__device__ __forceinline__ void gemm_bf16_body(const void* __restrict__ Aptr,
                                               const float* __restrict__ B,
                                               void* __restrict__ Cptr,
                                               int M, int N, int K,
                                               int bx, int by) {
    __shared__ unsigned short As[2][64][72];
    __shared__ unsigned short Bs[2][32][72];

    const int t  = threadIdx.x;
    const int m0 = by * 64;
    const int n0 = bx * 32;
    const int rl = t >> 2;          // 0..63 (A row / B k-row)
    const int c4 = (t & 3) * 16;    // A col offset (elements)
    const int nc = (t & 3) * 8;     // B col offset (8 cols/thread)

    const int lane = t & 63, w = t >> 6, lr = lane & 15, quad = lane >> 4;

    f32x4 acc[2] = {{0.f,0.f,0.f,0.f},{0.f,0.f,0.f,0.f}};

    float4 fa[4]; bf16x8 ba[2]; float4 fb[2];
    auto LDA = [&](int k0) {
        if (ABF16) {
            const unsigned short* A = (const unsigned short*)Aptr;
            ba[0] = *(const bf16x8*)&A[(size_t)(m0 + rl) * K + k0 + c4];
            ba[1] = *(const bf16x8*)&A[(size_t)(m0 + rl) * K + k0 + c4 + 8];
        } else {
            const float* A = (const float*)Aptr;
            const float* p = &A[(size_t)(m0 + rl) * K + k0 + c4];
            fa[0] = *(const float4*)&p[0];  fa[1] = *(const float4*)&p[4];
            fa[2] = *(const float4*)&p[8];  fa[3] = *(const float4*)&p[12];
        }
    };
    auto LDB = [&](int k0) {   // 64x32 B tile: row rl, cols nc..nc+7
        const float* p = &B[(size_t)(k0 + rl) * N + n0 + nc];
        fb[0] = *(const float4*)&p[0];  fb[1] = *(const float4*)&p[4];
    };
    auto STORE = [&](int pp) {
        if (ABF16) {
            *(bf16x8*)&As[pp][rl][c4]     = ba[0];
            *(bf16x8*)&As[pp][rl][c4 + 8] = ba[1];
        } else {
            *(bf16x8*)&As[pp][rl][c4]     = pack8(fa[0], fa[1]);
            *(bf16x8*)&As[pp][rl][c4 + 8] = pack8(fa[2], fa[3]);
        }
        // B transpose: Bs[n][k] — 8 scalar stores/thread.
        Bs[pp][nc + 0][rl] = f2b(fb[0].x);
        Bs[pp][nc + 1][rl] = f2b(fb[0].y);
        Bs[pp][nc + 2][rl] = f2b(fb[0].z);
        Bs[pp][nc + 3][rl] = f2b(fb[0].w);
        Bs[pp][nc + 4][rl] = f2b(fb[1].x);
        Bs[pp][nc + 5][rl] = f2b(fb[1].y);
        Bs[pp][nc + 6][rl] = f2b(fb[1].z);
        Bs[pp][nc + 7][rl] = f2b(fb[1].w);
    };

    LDA(0); LDB(0);
    STORE(0);
    __syncthreads();

    int p = 0;
    for (int k0 = 0; k0 < K; k0 += 64) {
        const bool more = (k0 + 64 < K);
        if (more) { LDA(k0 + 64); LDB(k0 + 64); }

        bf16x8 a0 = *(const bf16x8*)&As[p][w * 16 + lr][quad * 8];
        bf16x8 a1 = *(const bf16x8*)&As[p][w * 16 + lr][32 + quad * 8];
        #pragma unroll
        for (int nt = 0; nt < 2; ++nt) {
            bf16x8 b0 = *(const bf16x8*)&Bs[p][nt * 16 + lr][quad * 8];
            bf16x8 b1 = *(const bf16x8*)&Bs[p][nt * 16 + lr][32 + quad * 8];
            acc[nt] = __builtin_amdgcn_mfma_f32_16x16x32_bf16(a0, b0, acc[nt], 0, 0, 0);
            acc[nt] = __builtin_amdgcn_mfma_f32_16x16x32_bf16(a1, b1, acc[nt], 0, 0, 0);
        }

        if (more) STORE(p ^ 1);   // p^1's last readers passed the previous
        __syncthreads();          // end-of-iteration barrier
        p ^= 1;
    }

    #pragma unroll
    for (int nt = 0; nt < 2; ++nt)
        #pragma unroll
        for (int r = 0; r < 4; ++r) {
            int m = m0 + w * 16 + quad * 4 + r;
            int n = n0 + nt * 16 + lr;
            if (CBF16) ((unsigned short*)Cptr)[(size_t)m * N + n] = f2b(acc[nt][r]);
            else       ((float*)Cptr)[(size_t)m * N + n] = acc[nt][r];
        }
}

// V projection -> bf16 (A = pre-packed xbf). bx==16 column = chunk_keys
// (r-ascending sum IDENTICAL -> ck bit-exact). Block (0,0) zeroes counters.
__global__ __launch_bounds__(256) void gemm_v(const unsigned short* __restrict__ xbf,
                                              const float* __restrict__ Wv,
                                              unsigned short* __restrict__ Vbf,
                                              int* __restrict__ cur,
                                              const float* __restrict__ K,
                                              float* __restrict__ ck) {
    if (blockIdx.x == 16) {
        const int c = blockIdx.y;              // 0..31
        const int t = threadIdx.x;
        #pragma unroll
        for (int dd = 0; dd < 2; ++dd) {
            const int d = t + dd * 256;        // 512 cols / 256 threads
            const float* p = K + (size_t)c * 64 * D_DIM + d;
            float sum = 0.f;
            #pragma unroll
            for (int r = 0; r < 64; ++r) sum += p[(size_t)r * D_DIM];
            ck[(size_t)c * D_DIM + d] = sum * (1.0f / 64.0f);
        }
        return;
    }
    if (blockIdx.x == 0 && blockIdx.y == 0) cur[threadIdx.x] = 0;
    gemm_bf16_body<true, true>(xbf, Wv, Vbf, S_LEN, D_DIM, D_DIM,
                               blockIdx.x, blockIdx.y);
}

// Output projection: bf16 A (normalized attention out), fp32 C.
__global__ __launch_bounds__(256) void gemm_out(const unsigned short* __restrict__ Obn,
                                                const float* __restrict__ Wo,
                                                float* __restrict__ out) {
    gemm_bf16_body<true, false>(Obn, Wo, out, S_LEN, D_DIM, D_DIM,
                                blockIdx.x, blockIdx.y);
}

// ---------------------------------------------------------------------------
// Fused sims + top-5 + scatter — R17 (single lever): 32-row half-tiles,
// 512 blocks = 2 blocks/CU. This exact decomposition ran BIT-EXACT as
// R11's mega phase 1; per-(row,chunk) sim FMA chain statement-identical
// (d4 ascending, j-inner per chunk); qlist order differs but attention is
// consumption-order-independent (absmax invariant R9-R16). R14's bundle
// regression is attributed to ABLK=8, not this.
// ---------------------------------------------------------------------------
__global__ __launch_bounds__(256) void sims_topk(const float* __restrict__ Q,
                                                 const float* __restrict__ ck,
                                                 int* __restrict__ cur,
                                                 unsigned short* __restrict__ qlist) {
    __shared__ float qtile[32][68];
    __shared__ float cks[32][68];
    __shared__ float simsb[32][36];
    __shared__ int   lds_cnt[32];
    __shared__ int   lds_base[32];

    const int t     = threadIdx.x;
    const int sbase = blockIdx.x * 32;
    const int h     = blockIdx.y;

    if (t < 32) lds_cnt[t] = 0;

    for (int i = t; i < 32 * 16; i += 256) {
        int r = i >> 4, cf4 = i & 15;
        *(float4*)&qtile[r][cf4 * 4] =
            *(const float4*)&Q[(size_t)(sbase + r) * D_DIM + h * HD + cf4 * 4];
    }
    for (int i = t; i < C_NUM * 16; i += 256) {
        int c = i >> 4, df4 = i & 15;
        *(float4*)&cks[c][df4 * 4] =
            *(const float4*)&ck[(size_t)c * D_DIM + h * HD + df4 * 4];
    }
    __syncthreads();

    {
        const int sl = t >> 3;      // 0..31 rows
        const int g  = t & 7;       // 8 groups x 4 chunks
        float sa[4] = {0.f, 0.f, 0.f, 0.f};
        #pragma unroll
        for (int d4 = 0; d4 < 16; ++d4) {
            float4 q4 = *(const float4*)&qtile[sl][d4 * 4];
            #pragma unroll
            for (int j = 0; j < 4; ++j) {
                float4 c4v = *(const float4*)&cks[g * 4 + j][d4 * 4];
                sa[j] += q4.x*c4v.x + q4.y*c4v.y + q4.z*c4v.z + q4.w*c4v.w;
            }
        }
        *(float4*)&simsb[sl][g * 4] = make_float4(sa[0], sa[1], sa[2], sa[3]);
    }
    __syncthreads();

    int csel[TOPK], lpos[TOPK];
    if (t < 32) {
        float sv[32];
        #pragma unroll
        for (int cq = 0; cq < 8; ++cq) {
            float4 v = *(const float4*)&simsb[t][cq * 4];
            sv[cq*4+0] = v.x; sv[cq*4+1] = v.y; sv[cq*4+2] = v.z; sv[cq*4+3] = v.w;
        }
        #pragma unroll
        for (int k = 0; k < TOPK; ++k) {
            float best = -INFINITY; int bi = 0;
            #pragma unroll
            for (int cc = 0; cc < 32; ++cc) {
                bool gt = sv[cc] > best;
                best = gt ? sv[cc] : best;
                bi   = gt ? cc : bi;
            }
            #pragma unroll
            for (int cc = 0; cc < 32; ++cc)
                if (cc == bi) sv[cc] = -INFINITY;
            csel[k] = bi;
            lpos[k] = atomicAdd(&lds_cnt[bi], 1);
        }
    }
    __syncthreads();

    if (t < 32) lds_base[t] = atomicAdd(&cur[h * 32 + t], lds_cnt[t]);
    __syncthreads();

    if (t < 32) {
        #pragma unroll
        for (int k = 0; k < TOPK; ++k) {
            int c = csel[k];
            int pos = lds_base[c] + lpos[k];
            if (pos < QCAP)
                qlist[(size_t)(h * 32 + c) * QCAP + pos] =
                    (unsigned short)((sbase + t) | (k << 11));
        }
    }
}

// ---------------------------------------------------------------------------
// MFMA chunk-centric attention v8 (R9 persistent-K/V barrier-free structure,
// R16 bf16-source staging, R15-verified ABLK=4). Bit-identical per query.
// ---------------------------------------------------------------------------
__global__ __launch_bounds__(256) void moc_attn8(const unsigned short* __restrict__ Qbf,
                                                 const unsigned short* __restrict__ Kbf,
                                                 const unsigned short* __restrict__ Vbf,
                                                 const int* __restrict__ cnt,
                                                 const unsigned short* __restrict__ qlist,
                                                 float* __restrict__ lpart,
                                                 float* __restrict__ Opart) {
    __shared__ unsigned short Qs[64][72];
    __shared__ unsigned short Ks[64][72];
    __shared__ unsigned short VT[64][72];
    __shared__ unsigned short Ps[64][72];
    __shared__ unsigned short slist[64];

    const int hc = blockIdx.y;
    const int h  = hc >> 5;
    const int c  = hc & 31;
    const int g0 = blockIdx.x;          // 0..ABLK-1
    const int t  = threadIdx.x;

    const int count  = min(cnt[hc], QCAP);
    const int ntiles = (count + 63) >> 6;
    if (g0 >= ntiles) return;

    const unsigned short* Kb = Kbf + ((size_t)c * 64) * D_DIM + h * HD;
    const unsigned short* Vb = Vbf + ((size_t)c * 64) * D_DIM + h * HD;

    const int j  = t >> 2;
    const int d0 = (t & 3) * 16;

    {   // K and V staged once for all tiles this block handles (bf16 direct).
        const unsigned short* kr = Kb + (size_t)j * D_DIM + d0;
        *(bf16x8*)&Ks[j][d0]     = *(const bf16x8*)&kr[0];
        *(bf16x8*)&Ks[j][d0 + 8] = *(const bf16x8*)&kr[8];

        const unsigned short* vr = Vb + (size_t)j * D_DIM + d0;
        bf16x8 v0 = *(const bf16x8*)&vr[0];
        bf16x8 v1 = *(const bf16x8*)&vr[8];
        #pragma unroll
        for (int i = 0; i < 8; ++i) {
            VT[d0 + i][j]     = (unsigned short)v0[i];
            VT[d0 + 8 + i][j] = (unsigned short)v1[i];
        }
    }
    __syncthreads();   // the ONLY block-wide barrier

    const int lane = t & 63;
    const int w    = t >> 6;
    const int lr   = lane & 15;
    const int quad = lane >> 4;

    for (int ti = g0; ti < ntiles; ti += ABLK) {
        const int base = ti * 64;
        const int lim  = min(count - base, 64);
        const unsigned short* list = qlist + (size_t)hc * QCAP + base;

        {
            unsigned short pv = (j < lim) ? list[j] : (unsigned short)0xFFFF;
            if ((t & 3) == 0) slist[j] = pv;
            int s = (pv == 0xFFFF) ? 0 : (int)(pv & 2047);
            const unsigned short* qr = Qbf + (size_t)s * D_DIM + h * HD + d0;
            *(bf16x8*)&Qs[j][d0]     = *(const bf16x8*)&qr[0];
            *(bf16x8*)&Qs[j][d0 + 8] = *(const bf16x8*)&qr[8];
        }
        // No barrier: Qs/slist rows this wave reads were written by this wave
        // (threads 4j..4j+3 of wave w cover rows w*16..+15).

        bf16x8 aq0 = *(const bf16x8*)&Qs[w * 16 + lr][quad * 8];
        bf16x8 aq1 = *(const bf16x8*)&Qs[w * 16 + lr][32 + quad * 8];

        f32x4 acc[4];
        #pragma unroll
        for (int kt = 0; kt < 4; ++kt) {
            bf16x8 b0 = *(const bf16x8*)&Ks[kt * 16 + lr][quad * 8];
            bf16x8 b1 = *(const bf16x8*)&Ks[kt * 16 + lr][32 + quad * 8];
            f32x4 z = {0.f, 0.f, 0.f, 0.f};
            z = __builtin_amdgcn_mfma_f32_16x16x32_bf16(aq0, b0, z, 0, 0, 0);
            z = __builtin_amdgcn_mfma_f32_16x16x32_bf16(aq1, b1, z, 0, 0, 0);
            acc[kt] = z;
        }

        unsigned short pb[4][4];
        float dsum[4] = {0.f, 0.f, 0.f, 0.f};
        #pragma unroll
        for (int kt = 0; kt < 4; ++kt) {
            #pragma unroll
            for (int r = 0; r < 4; ++r) {
                unsigned short u = f2b(__expf(acc[kt][r] * SCALE));
                pb[kt][r] = u;
                dsum[r] += b2f(u);
            }
        }
        #pragma unroll
        for (int r = 0; r < 4; ++r) {
            float v = dsum[r];
            v += __shfl_xor(v, 1, 64);
            v += __shfl_xor(v, 2, 64);
            v += __shfl_xor(v, 4, 64);
            v += __shfl_xor(v, 8, 64);
            dsum[r] = v;
        }
        if (lr == 0) {
            #pragma unroll
            for (int r = 0; r < 4; ++r) {
                unsigned short sv = slist[w * 16 + quad * 4 + r];
                if (sv != 0xFFFF) {
                    int kk = sv >> 11, s = sv & 2047;
                    lpart[((size_t)kk * H_NUM + h) * S_LEN + s] = dsum[r];
                }
            }
        }

        #pragma unroll
        for (int kt = 0; kt < 4; ++kt)
            #pragma unroll
            for (int r = 0; r < 4; ++r)
                Ps[w * 16 + quad * 4 + r][kt * 16 + lr] = pb[kt][r];

        bf16x8 ap0 = *(const bf16x8*)&Ps[w * 16 + lr][quad * 8];
        bf16x8 ap1 = *(const bf16x8*)&Ps[w * 16 + lr][32 + quad * 8];

        #pragma unroll
        for (int dt = 0; dt < 4; ++dt) {
            bf16x8 b0 = *(const bf16x8*)&VT[dt * 16 + lr][quad * 8];
            bf16x8 b1 = *(const bf16x8*)&VT[dt * 16 + lr][32 + quad * 8];
            f32x4 z = {0.f, 0.f, 0.f, 0.f};
            z = __builtin_amdgcn_mfma_f32_16x16x32_bf16(ap0, b0, z, 0, 0, 0);
            z = __builtin_amdgcn_mfma_f32_16x16x32_bf16(ap1, b1, z, 0, 0, 0);
            #pragma unroll
            for (int r = 0; r < 4; ++r) {
                unsigned short sv = slist[w * 16 + quad * 4 + r];
                if (sv != 0xFFFF) {
                    int kk = sv >> 11, s = sv & 2047;
                    Opart[((((size_t)kk * H_NUM + h) * S_LEN + s) * HD) + dt * 16 + lr] = z[r];
                }
            }
        }
    }
}

// ---------------------------------------------------------------------------
// Obn_bf[s][h*64+d] = bf16( (sum_k Opart[k][h][s][d]) / (sum_k lpart) )
// ---------------------------------------------------------------------------
__global__ __launch_bounds__(256) void reduce_norm(const float4* __restrict__ Opart4,
                                                   const float* __restrict__ lpart,
                                                   unsigned short* __restrict__ Obn) {
    int i = blockIdx.x * 256 + threadIdx.x;   // one float4-slot per thread
    int s    = i >> 7;
    int col4 = i & 127;
    int h    = col4 >> 4;
    int f4   = col4 & 15;
    float4 acc = make_float4(0.f,0.f,0.f,0.f);
    float  den = 0.f;
    #pragma unroll
    for (int k = 0; k < TOPK; ++k) {
        size_t slot = ((size_t)k * H_NUM + h) * S_LEN + s;
        float4 v = Opart4[slot * 16 + f4];
        acc.x += v.x; acc.y += v.y; acc.z += v.z; acc.w += v.w;
        den += lpart[slot];
    }
    float inv = 1.0f / den;
    us4 o;
    o[0] = f2b(acc.x * inv); o[1] = f2b(acc.y * inv);
    o[2] = f2b(acc.z * inv); o[3] = f2b(acc.w * inv);
    *(us4*)&Obn[(size_t)i * 4] = o;
}

// ---------------------------------------------------------------------------
// Workspace: Qb 4MB (reused as Obn bf16 2MB) | Kb 4MB | Vbf ushort 2MB
//   | ck 64KB | lpart 320KB | cur 1KB | qlist 512KB | Opart 20MB
//   | xbf 2MB | Qbf 2MB | Kbf 2MB  ≈ 37 MB
// ---------------------------------------------------------------------------
extern "C" void kernel_launch(void* const* d_in, const int* in_sizes, int n_in,
                              void* d_out, int out_size, void* d_ws, size_t ws_size,
                              hipStream_t stream) {
    const float* x  = (const float*)d_in[0];
    const float* Wq = (const float*)d_in[1];
    const float* Wk = (const float*)d_in[2];
    const float* Wv = (const float*)d_in[3];
    const float* Wo = (const float*)d_in[4];
    float* out = (float*)d_out;

    const size_t SD = (size_t)S_LEN * D_DIM;
    float* ws    = (float*)d_ws;
    float* Qb    = ws;                                    // later: Obn (bf16)
    float* Kb    = Qb + SD;
    unsigned short* Vbf = (unsigned short*)(Kb + SD);     // [2048][512] bf16
    float* ck    = (float*)(Vbf + SD);
    float* lpart = ck + (size_t)C_NUM * D_DIM;
    int*   curb  = (int*)(lpart + (size_t)TOPK * H_NUM * S_LEN);
    unsigned short* qlst = (unsigned short*)(curb + 256);
    float* Opart = (float*)(qlst + (size_t)256 * QCAP);
    unsigned short* xbf = (unsigned short*)(Opart + (size_t)TOPK * H_NUM * S_LEN * HD);
    unsigned short* Qbf = xbf + SD;
    unsigned short* Kbf = Qbf + SD;
    unsigned short* Obn = (unsigned short*)Qb;

    dim3 qkgrid(D_DIM / BN, S_LEN / BM, 2);      // Q,K fp32 + bf16 copies
    gemm_qkv<<<qkgrid, 256, 0, stream>>>(x, Wq, Wk, Qb, Kb, Qbf, Kbf, xbf);

    // V bf16 MFMA 64x32 tiles (A = xbf) + cur zeroing + chunk_keys (bx==16)
    dim3 vgrid(D_DIM / 32 + 1, S_LEN / 64);      // 17 x 32 = 544 blocks
    gemm_v<<<vgrid, 256, 0, stream>>>(xbf, Wv, Vbf, curb, Kb, ck);

    dim3 rgrid(S_LEN / 32, H_NUM);               // 64 x 8 = 512 blocks
    sims_topk<<<rgrid, 256, 0, stream>>>(Qb, ck, curb, qlst);

    dim3 agrid(ABLK, H_NUM * C_NUM);             // persistent K/V, 4 blk/hc
    moc_attn8<<<agrid, 256, 0, stream>>>(Qbf, Kbf, Vbf, curb, qlst, lpart, Opart);

    reduce_norm<<<(int)(SD / 4 / 256), 256, 0, stream>>>((const float4*)Opart, lpart, Obn);

    dim3 ogrid(D_DIM / 32, S_LEN / 64);          // 16 x 32 = 512 blocks
    gemm_out<<<ogrid, 256, 0, stream>>>(Obn, Wo, out);
}

// Round 18
// 140.469 us; speedup vs baseline: 1.0094x; 1.0094x over previous
//
#include <hip/hip_runtime.h>
#include <hip/hip_bf16.h>
#include <math.h>

// Problem constants (B=1)
#define S_LEN 2048
#define D_DIM 512
#define H_NUM 8
#define HD    64
#define C_NUM 32
#define TOPK  5
#define SCALE 0.125f   // hd^-0.5
#define QCAP  1024     // fixed qlist capacity per (h,c); load is ~320
#define ABLK  4        // attn blocks per (h,c)  (R15-verified)

typedef __attribute__((ext_vector_type(8))) short bf16x8;   // 8 bf16 (4 VGPRs)
typedef __attribute__((ext_vector_type(4))) float f32x4;
typedef __attribute__((ext_vector_type(4))) unsigned short us4;

__device__ __forceinline__ unsigned short f2b(float f) {
    __hip_bfloat16 h = __float2bfloat16(f);
    unsigned short u;
    __builtin_memcpy(&u, &h, 2);
    return u;
}
__device__ __forceinline__ bf16x8 pack8(float4 a, float4 b) {
    bf16x8 r;
    r[0] = (short)f2b(a.x); r[1] = (short)f2b(a.y);
    r[2] = (short)f2b(a.z); r[3] = (short)f2b(a.w);
    r[4] = (short)f2b(b.x); r[5] = (short)f2b(b.y);
    r[6] = (short)f2b(b.z); r[7] = (short)f2b(b.w);
    return r;
}
__device__ __forceinline__ float b2f(unsigned short u) {
    __hip_bfloat16 h;
    __builtin_memcpy(&h, &u, 2);
    return __bfloat162float(h);
}
__device__ __forceinline__ us4 pack4(float4 v) {
    us4 o;
    o[0] = f2b(v.x); o[1] = f2b(v.y); o[2] = f2b(v.z); o[3] = f2b(v.w);
    return o;
}

// ---------------------------------------------------------------------------
// fp32 GEMM (R0-EXACT FMA CHAIN — 43us floor, CLOSED; routing-critical,
// k-ascending, do not touch). R16: epilogue also writes bf16 C copy from
// the same acc registers (feeds attention staging; bit-identical).
// Session lessons: R11 grid.sync costs 10s of us — separate dispatches.
// R14: at the <=2us/lever scale, bundle nothing. R17: sims half-tiles
// rejected in isolation (64-row tiling is the winner).
// ---------------------------------------------------------------------------
#define BM 64
#define BN 64
#define BK 32

__device__ __forceinline__ void gemm_body(const float* __restrict__ A,
                                          const float* __restrict__ B,
                                          float* __restrict__ C,
                                          unsigned short* __restrict__ Cbf,
                                          int M, int N, int K,
                                          int bx, int by) {
    __shared__ float As[BK][BM + 4];
    __shared__ float Bs[BK][BN];

    const int t  = threadIdx.x;
    const int tx = t & 15;
    const int ty = t >> 4;
    const int m0 = by * BM;
    const int n0 = bx * BN;

    float4 acc0 = make_float4(0.f,0.f,0.f,0.f);
    float4 acc1 = make_float4(0.f,0.f,0.f,0.f);
    float4 acc2 = make_float4(0.f,0.f,0.f,0.f);
    float4 acc3 = make_float4(0.f,0.f,0.f,0.f);

    const int ar = t >> 3;
    const int ac = (t & 7) * 4;
    const int br = t >> 4;
    const int bc = (t & 15) * 4;

    float4 a0, a1, b0, b1;
    auto LD = [&](int k0) {
        a0 = *(const float4*)&A[(size_t)(m0 + ar)      * K + k0 + ac];
        a1 = *(const float4*)&A[(size_t)(m0 + ar + 32) * K + k0 + ac];
        b0 = *(const float4*)&B[(size_t)(k0 + br)      * N + n0 + bc];
        b1 = *(const float4*)&B[(size_t)(k0 + br + 16) * N + n0 + bc];
    };

    LD(0);
    for (int k0 = 0; k0 < K; k0 += BK) {
        __syncthreads();
        As[ac+0][ar]    = a0.x; As[ac+1][ar]    = a0.y; As[ac+2][ar]    = a0.z; As[ac+3][ar]    = a0.w;
        As[ac+0][ar+32] = a1.x; As[ac+1][ar+32] = a1.y; As[ac+2][ar+32] = a1.z; As[ac+3][ar+32] = a1.w;
        *(float4*)&Bs[br][bc]      = b0;
        *(float4*)&Bs[br + 16][bc] = b1;
        __syncthreads();

        if (k0 + BK < K) LD(k0 + BK);

        #pragma unroll
        for (int kk = 0; kk < BK; ++kk) {
            float4 a = *(const float4*)&As[kk][ty * 4];
            float4 b = *(const float4*)&Bs[kk][tx * 4];
            acc0.x += a.x*b.x; acc0.y += a.x*b.y; acc0.z += a.x*b.z; acc0.w += a.x*b.w;
            acc1.x += a.y*b.x; acc1.y += a.y*b.y; acc1.z += a.y*b.z; acc1.w += a.y*b.w;
            acc2.x += a.z*b.x; acc2.y += a.z*b.y; acc2.z += a.z*b.z; acc2.w += a.z*b.w;
            acc3.x += a.w*b.x; acc3.y += a.w*b.y; acc3.z += a.w*b.z; acc3.w += a.w*b.w;
        }
    }

    *(float4*)&C[(size_t)(m0 + ty*4 + 0) * N + n0 + tx*4] = acc0;
    *(float4*)&C[(size_t)(m0 + ty*4 + 1) * N + n0 + tx*4] = acc1;
    *(float4*)&C[(size_t)(m0 + ty*4 + 2) * N + n0 + tx*4] = acc2;
    *(float4*)&C[(size_t)(m0 + ty*4 + 3) * N + n0 + tx*4] = acc3;

    *(us4*)&Cbf[(size_t)(m0 + ty*4 + 0) * N + n0 + tx*4] = pack4(acc0);
    *(us4*)&Cbf[(size_t)(m0 + ty*4 + 1) * N + n0 + tx*4] = pack4(acc1);
    *(us4*)&Cbf[(size_t)(m0 + ty*4 + 2) * N + n0 + tx*4] = pack4(acc2);
    *(us4*)&Cbf[(size_t)(m0 + ty*4 + 3) * N + n0 + tx*4] = pack4(acc3);
}

// Q and K projections (z in {0,1}); fp32 math byte-identical to R0.
// Writes Qb/Kb (fp32, routing) + Qbf/Kbf (bf16, attention staging).
// Split xbf tail-pack (R15-verified).
__global__ __launch_bounds__(256) void gemm_qkv(const float* __restrict__ A,
                                                const float* __restrict__ Wq,
                                                const float* __restrict__ Wk,
                                                float* __restrict__ Qb,
                                                float* __restrict__ Kb,
                                                unsigned short* __restrict__ Qbf,
                                                unsigned short* __restrict__ Kbf,
                                                unsigned short* __restrict__ xbf) {
    const float* B = (blockIdx.z == 0) ? Wq : Wk;
    float*       C = (blockIdx.z == 0) ? Qb : Kb;
    unsigned short* Cbf = (blockIdx.z == 0) ? Qbf : Kbf;
    gemm_body(A, B, C, Cbf, S_LEN, D_DIM, D_DIM, blockIdx.x, blockIdx.y);
    {
        const int r0 = blockIdx.y * 64 + (int)blockIdx.z * 32;  // half-tile
        const int c0 = blockIdx.x * 64;
        for (int i = threadIdx.x; i < 32 * 16; i += 256) {
            int r = i >> 4, c4 = (i & 15) * 4;
            float4 v = *(const float4*)&A[(size_t)(r0 + r) * D_DIM + c0 + c4];
            *(us4*)&xbf[(size_t)(r0 + r) * D_DIM + c0 + c4] = pack4(v);
        }
    }
}

// ---------------------------------------------------------------------------
// bf16 MFMA GEMM — 64x32 tile (R13 win: 2 blocks/CU), dbuf one barrier per
// K-step (R10 win). Per-output MFMA chain statement-identical.
// ---------------------------------------------------------------------------
template <bool ABF16, bool CBF16>
__device__ __forceinline__ void gemm_bf16_body(const void* __restrict__ Aptr,
                                               const float* __restrict__ B,
                                               void* __restrict__ Cptr,
                                               int M, int N, int K,
                                               int bx, int by) {
    __shared__ unsigned short As[2][64][72];
    __shared__ unsigned short Bs[2][32][72];

    const int t  = threadIdx.x;
    const int m0 = by * 64;
    const int n0 = bx * 32;
    const int rl = t >> 2;          // 0..63 (A row / B k-row)
    const int c4 = (t & 3) * 16;    // A col offset (elements)
    const int nc = (t & 3) * 8;     // B col offset (8 cols/thread)

    const int lane = t & 63, w = t >> 6, lr = lane & 15, quad = lane >> 4;

    f32x4 acc[2] = {{0.f,0.f,0.f,0.f},{0.f,0.f,0.f,0.f}};

    float4 fa[4]; bf16x8 ba[2]; float4 fb[2];
    auto LDA = [&](int k0) {
        if (ABF16) {
            const unsigned short* A = (const unsigned short*)Aptr;
            ba[0] = *(const bf16x8*)&A[(size_t)(m0 + rl) * K + k0 + c4];
            ba[1] = *(const bf16x8*)&A[(size_t)(m0 + rl) * K + k0 + c4 + 8];
        } else {
            const float* A = (const float*)Aptr;
            const float* p = &A[(size_t)(m0 + rl) * K + k0 + c4];
            fa[0] = *(const float4*)&p[0];  fa[1] = *(const float4*)&p[4];
            fa[2] = *(const float4*)&p[8];  fa[3] = *(const float4*)&p[12];
        }
    };
    auto LDB = [&](int k0) {   // 64x32 B tile: row rl, cols nc..nc+7
        const float* p = &B[(size_t)(k0 + rl) * N + n0 + nc];
        fb[0] = *(const float4*)&p[0];  fb[1] = *(const float4*)&p[4];
    };
    auto STORE = [&](int pp) {
        if (ABF16) {
            *(bf16x8*)&As[pp][rl][c4]     = ba[0];
            *(bf16x8*)&As[pp][rl][c4 + 8] = ba[1];
        } else {
            *(bf16x8*)&As[pp][rl][c4]     = pack8(fa[0], fa[1]);
            *(bf16x8*)&As[pp][rl][c4 + 8] = pack8(fa[2], fa[3]);
        }
        // B transpose: Bs[n][k] — 8 scalar stores/thread.
        Bs[pp][nc + 0][rl] = f2b(fb[0].x);
        Bs[pp][nc + 1][rl] = f2b(fb[0].y);
        Bs[pp][nc + 2][rl] = f2b(fb[0].z);
        Bs[pp][nc + 3][rl] = f2b(fb[0].w);
        Bs[pp][nc + 4][rl] = f2b(fb[1].x);
        Bs[pp][nc + 5][rl] = f2b(fb[1].y);
        Bs[pp][nc + 6][rl] = f2b(fb[1].z);
        Bs[pp][nc + 7][rl] = f2b(fb[1].w);
    };

    LDA(0); LDB(0);
    STORE(0);
    __syncthreads();

    int p = 0;
    for (int k0 = 0; k0 < K; k0 += 64) {
        const bool more = (k0 + 64 < K);
        if (more) { LDA(k0 + 64); LDB(k0 + 64); }

        bf16x8 a0 = *(const bf16x8*)&As[p][w * 16 + lr][quad * 8];
        bf16x8 a1 = *(const bf16x8*)&As[p][w * 16 + lr][32 + quad * 8];
        #pragma unroll
        for (int nt = 0; nt < 2; ++nt) {
            bf16x8 b0 = *(const bf16x8*)&Bs[p][nt * 16 + lr][quad * 8];
            bf16x8 b1 = *(const bf16x8*)&Bs[p][nt * 16 + lr][32 + quad * 8];
            acc[nt] = __builtin_amdgcn_mfma_f32_16x16x32_bf16(a0, b0, acc[nt], 0, 0, 0);
            acc[nt] = __builtin_amdgcn_mfma_f32_16x16x32_bf16(a1, b1, acc[nt], 0, 0, 0);
        }

        if (more) STORE(p ^ 1);   // p^1's last readers passed the previous
        __syncthreads();          // end-of-iteration barrier
        p ^= 1;
    }

    #pragma unroll
    for (int nt = 0; nt < 2; ++nt)
        #pragma unroll
        for (int r = 0; r < 4; ++r) {
            int m = m0 + w * 16 + quad * 4 + r;
            int n = n0 + nt * 16 + lr;
            if (CBF16) ((unsigned short*)Cptr)[(size_t)m * N + n] = f2b(acc[nt][r]);
            else       ((float*)Cptr)[(size_t)m * N + n] = acc[nt][r];
        }
}

// V projection -> bf16 (A = pre-packed xbf). bx==16 column = chunk_keys
// (r-ascending sum IDENTICAL -> ck bit-exact). Block (0,0) zeroes counters.
__global__ __launch_bounds__(256) void gemm_v(const unsigned short* __restrict__ xbf,
                                              const float* __restrict__ Wv,
                                              unsigned short* __restrict__ Vbf,
                                              int* __restrict__ cur,
                                              const float* __restrict__ K,
                                              float* __restrict__ ck) {
    if (blockIdx.x == 16) {
        const int c = blockIdx.y;              // 0..31
        const int t = threadIdx.x;
        #pragma unroll
        for (int dd = 0; dd < 2; ++dd) {
            const int d = t + dd * 256;        // 512 cols / 256 threads
            const float* p = K + (size_t)c * 64 * D_DIM + d;
            float sum = 0.f;
            #pragma unroll
            for (int r = 0; r < 64; ++r) sum += p[(size_t)r * D_DIM];
            ck[(size_t)c * D_DIM + d] = sum * (1.0f / 64.0f);
        }
        return;
    }
    if (blockIdx.x == 0 && blockIdx.y == 0) cur[threadIdx.x] = 0;
    gemm_bf16_body<true, true>(xbf, Wv, Vbf, S_LEN, D_DIM, D_DIM,
                               blockIdx.x, blockIdx.y);
}

// Output projection: bf16 A (normalized attention out), fp32 C.
__global__ __launch_bounds__(256) void gemm_out(const unsigned short* __restrict__ Obn,
                                                const float* __restrict__ Wo,
                                                float* __restrict__ out) {
    gemm_bf16_body<true, false>(Obn, Wo, out, S_LEN, D_DIM, D_DIM,
                                blockIdx.x, blockIdx.y);
}

// ---------------------------------------------------------------------------
// Fused sims + top-5 + scatter (R16 config: 64-row tiles — measured winner;
// R17's 32-row half-tiles rejected in isolation). fp32, routing-faithful.
// ---------------------------------------------------------------------------
__global__ __launch_bounds__(256) void sims_topk(const float* __restrict__ Q,
                                                 const float* __restrict__ ck,
                                                 int* __restrict__ cur,
                                                 unsigned short* __restrict__ qlist) {
    __shared__ float qtile[64][68];
    __shared__ float cks[32][68];
    __shared__ float simsb[64][36];
    __shared__ int   lds_cnt[32];
    __shared__ int   lds_base[32];

    const int t  = threadIdx.x;
    const int s0 = blockIdx.x * 64;
    const int h  = blockIdx.y;

    if (t < 32) lds_cnt[t] = 0;

    {
        int r = t >> 2;
        #pragma unroll
        for (int i = 0; i < 4; ++i) {
            int cf4 = (t & 3) * 4 + i;
            *(float4*)&qtile[r][cf4 * 4] =
                *(const float4*)&Q[(size_t)(s0 + r) * D_DIM + h * HD + cf4 * 4];
        }
    }
    for (int i = t; i < C_NUM * 16; i += 256) {
        int c = i >> 4, df4 = i & 15;
        *(float4*)&cks[c][df4 * 4] =
            *(const float4*)&ck[(size_t)c * D_DIM + h * HD + df4 * 4];
    }
    __syncthreads();

    {
        const int sl = t >> 2, g = t & 3;
        float sa[8] = {0.f,0.f,0.f,0.f,0.f,0.f,0.f,0.f};
        #pragma unroll
        for (int d4 = 0; d4 < 16; ++d4) {
            float4 q4 = *(const float4*)&qtile[sl][d4 * 4];
            #pragma unroll
            for (int j = 0; j < 8; ++j) {
                float4 c4 = *(const float4*)&cks[g * 8 + j][d4 * 4];
                sa[j] += q4.x*c4.x + q4.y*c4.y + q4.z*c4.z + q4.w*c4.w;
            }
        }
        *(float4*)&simsb[sl][g*8 + 0] = make_float4(sa[0], sa[1], sa[2], sa[3]);
        *(float4*)&simsb[sl][g*8 + 4] = make_float4(sa[4], sa[5], sa[6], sa[7]);
    }
    __syncthreads();

    int csel[TOPK], lpos[TOPK];
    if (t < 64) {
        float sv[32];
        #pragma unroll
        for (int cq = 0; cq < 8; ++cq) {
            float4 v = *(const float4*)&simsb[t][cq * 4];
            sv[cq*4+0] = v.x; sv[cq*4+1] = v.y; sv[cq*4+2] = v.z; sv[cq*4+3] = v.w;
        }
        #pragma unroll
        for (int k = 0; k < TOPK; ++k) {
            float best = -INFINITY; int bi = 0;
            #pragma unroll
            for (int cc = 0; cc < 32; ++cc) {
                bool gt = sv[cc] > best;
                best = gt ? sv[cc] : best;
                bi   = gt ? cc : bi;
            }
            #pragma unroll
            for (int cc = 0; cc < 32; ++cc)
                if (cc == bi) sv[cc] = -INFINITY;
            csel[k] = bi;
            lpos[k] = atomicAdd(&lds_cnt[bi], 1);
        }
    }
    __syncthreads();

    if (t < 32) lds_base[t] = atomicAdd(&cur[h * 32 + t], lds_cnt[t]);
    __syncthreads();

    if (t < 64) {
        #pragma unroll
        for (int k = 0; k < TOPK; ++k) {
            int c = csel[k];
            int pos = lds_base[c] + lpos[k];
            if (pos < QCAP)
                qlist[(size_t)(h * 32 + c) * QCAP + pos] =
                    (unsigned short)((s0 + t) | (k << 11));
        }
    }
}

// ---------------------------------------------------------------------------
// MFMA chunk-centric attention v8 (R9 persistent-K/V barrier-free structure,
// R16 bf16-source staging, R15-verified ABLK=4). Bit-identical per query.
// ---------------------------------------------------------------------------
__global__ __launch_bounds__(256) void moc_attn8(const unsigned short* __restrict__ Qbf,
                                                 const unsigned short* __restrict__ Kbf,
                                                 const unsigned short* __restrict__ Vbf,
                                                 const int* __restrict__ cnt,
                                                 const unsigned short* __restrict__ qlist,
                                                 float* __restrict__ lpart,
                                                 float* __restrict__ Opart) {
    __shared__ unsigned short Qs[64][72];
    __shared__ unsigned short Ks[64][72];
    __shared__ unsigned short VT[64][72];
    __shared__ unsigned short Ps[64][72];
    __shared__ unsigned short slist[64];

    const int hc = blockIdx.y;
    const int h  = hc >> 5;
    const int c  = hc & 31;
    const int g0 = blockIdx.x;          // 0..ABLK-1
    const int t  = threadIdx.x;

    const int count  = min(cnt[hc], QCAP);
    const int ntiles = (count + 63) >> 6;
    if (g0 >= ntiles) return;

    const unsigned short* Kb = Kbf + ((size_t)c * 64) * D_DIM + h * HD;
    const unsigned short* Vb = Vbf + ((size_t)c * 64) * D_DIM + h * HD;

    const int j  = t >> 2;
    const int d0 = (t & 3) * 16;

    {   // K and V staged once for all tiles this block handles (bf16 direct).
        const unsigned short* kr = Kb + (size_t)j * D_DIM + d0;
        *(bf16x8*)&Ks[j][d0]     = *(const bf16x8*)&kr[0];
        *(bf16x8*)&Ks[j][d0 + 8] = *(const bf16x8*)&kr[8];

        const unsigned short* vr = Vb + (size_t)j * D_DIM + d0;
        bf16x8 v0 = *(const bf16x8*)&vr[0];
        bf16x8 v1 = *(const bf16x8*)&vr[8];
        #pragma unroll
        for (int i = 0; i < 8; ++i) {
            VT[d0 + i][j]     = (unsigned short)v0[i];
            VT[d0 + 8 + i][j] = (unsigned short)v1[i];
        }
    }
    __syncthreads();   // the ONLY block-wide barrier

    const int lane = t & 63;
    const int w    = t >> 6;
    const int lr   = lane & 15;
    const int quad = lane >> 4;

    for (int ti = g0; ti < ntiles; ti += ABLK) {
        const int base = ti * 64;
        const int lim  = min(count - base, 64);
        const unsigned short* list = qlist + (size_t)hc * QCAP + base;

        {
            unsigned short pv = (j < lim) ? list[j] : (unsigned short)0xFFFF;
            if ((t & 3) == 0) slist[j] = pv;
            int s = (pv == 0xFFFF) ? 0 : (int)(pv & 2047);
            const unsigned short* qr = Qbf + (size_t)s * D_DIM + h * HD + d0;
            *(bf16x8*)&Qs[j][d0]     = *(const bf16x8*)&qr[0];
            *(bf16x8*)&Qs[j][d0 + 8] = *(const bf16x8*)&qr[8];
        }
        // No barrier: Qs/slist rows this wave reads were written by this wave
        // (threads 4j..4j+3 of wave w cover rows w*16..+15).

        bf16x8 aq0 = *(const bf16x8*)&Qs[w * 16 + lr][quad * 8];
        bf16x8 aq1 = *(const bf16x8*)&Qs[w * 16 + lr][32 + quad * 8];

        f32x4 acc[4];
        #pragma unroll
        for (int kt = 0; kt < 4; ++kt) {
            bf16x8 b0 = *(const bf16x8*)&Ks[kt * 16 + lr][quad * 8];
            bf16x8 b1 = *(const bf16x8*)&Ks[kt * 16 + lr][32 + quad * 8];
            f32x4 z = {0.f, 0.f, 0.f, 0.f};
            z = __builtin_amdgcn_mfma_f32_16x16x32_bf16(aq0, b0, z, 0, 0, 0);
            z = __builtin_amdgcn_mfma_f32_16x16x32_bf16(aq1, b1, z, 0, 0, 0);
            acc[kt] = z;
        }

        unsigned short pb[4][4];
        float dsum[4] = {0.f, 0.f, 0.f, 0.f};
        #pragma unroll
        for (int kt = 0; kt < 4; ++kt) {
            #pragma unroll
            for (int r = 0; r < 4; ++r) {
                unsigned short u = f2b(__expf(acc[kt][r] * SCALE));
                pb[kt][r] = u;
                dsum[r] += b2f(u);
            }
        }
        #pragma unroll
        for (int r = 0; r < 4; ++r) {
            float v = dsum[r];
            v += __shfl_xor(v, 1, 64);
            v += __shfl_xor(v, 2, 64);
            v += __shfl_xor(v, 4, 64);
            v += __shfl_xor(v, 8, 64);
            dsum[r] = v;
        }
        if (lr == 0) {
            #pragma unroll
            for (int r = 0; r < 4; ++r) {
                unsigned short sv = slist[w * 16 + quad * 4 + r];
                if (sv != 0xFFFF) {
                    int kk = sv >> 11, s = sv & 2047;
                    lpart[((size_t)kk * H_NUM + h) * S_LEN + s] = dsum[r];
                }
            }
        }

        #pragma unroll
        for (int kt = 0; kt < 4; ++kt)
            #pragma unroll
            for (int r = 0; r < 4; ++r)
                Ps[w * 16 + quad * 4 + r][kt * 16 + lr] = pb[kt][r];

        bf16x8 ap0 = *(const bf16x8*)&Ps[w * 16 + lr][quad * 8];
        bf16x8 ap1 = *(const bf16x8*)&Ps[w * 16 + lr][32 + quad * 8];

        #pragma unroll
        for (int dt = 0; dt < 4; ++dt) {
            bf16x8 b0 = *(const bf16x8*)&VT[dt * 16 + lr][quad * 8];
            bf16x8 b1 = *(const bf16x8*)&VT[dt * 16 + lr][32 + quad * 8];
            f32x4 z = {0.f, 0.f, 0.f, 0.f};
            z = __builtin_amdgcn_mfma_f32_16x16x32_bf16(ap0, b0, z, 0, 0, 0);
            z = __builtin_amdgcn_mfma_f32_16x16x32_bf16(ap1, b1, z, 0, 0, 0);
            #pragma unroll
            for (int r = 0; r < 4; ++r) {
                unsigned short sv = slist[w * 16 + quad * 4 + r];
                if (sv != 0xFFFF) {
                    int kk = sv >> 11, s = sv & 2047;
                    Opart[((((size_t)kk * H_NUM + h) * S_LEN + s) * HD) + dt * 16 + lr] = z[r];
                }
            }
        }
    }
}

// ---------------------------------------------------------------------------
// Obn_bf[s][h*64+d] = bf16( (sum_k Opart[k][h][s][d]) / (sum_k lpart) )
// ---------------------------------------------------------------------------
__global__ __launch_bounds__(256) void reduce_norm(const float4* __restrict__ Opart4,
                                                   const float* __restrict__ lpart,
                                                   unsigned short* __restrict__ Obn) {
    int i = blockIdx.x * 256 + threadIdx.x;   // one float4-slot per thread
    int s    = i >> 7;
    int col4 = i & 127;
    int h    = col4 >> 4;
    int f4   = col4 & 15;
    float4 acc = make_float4(0.f,0.f,0.f,0.f);
    float  den = 0.f;
    #pragma unroll
    for (int k = 0; k < TOPK; ++k) {
        size_t slot = ((size_t)k * H_NUM + h) * S_LEN + s;
        float4 v = Opart4[slot * 16 + f4];
        acc.x += v.x; acc.y += v.y; acc.z += v.z; acc.w += v.w;
        den += lpart[slot];
    }
    float inv = 1.0f / den;
    us4 o;
    o[0] = f2b(acc.x * inv); o[1] = f2b(acc.y * inv);
    o[2] = f2b(acc.z * inv); o[3] = f2b(acc.w * inv);
    *(us4*)&Obn[(size_t)i * 4] = o;
}

// ---------------------------------------------------------------------------
// Workspace: Qb 4MB (reused as Obn bf16 2MB) | Kb 4MB | Vbf ushort 2MB
//   | ck 64KB | lpart 320KB | cur 1KB | qlist 512KB | Opart 20MB
//   | xbf 2MB | Qbf 2MB | Kbf 2MB  ≈ 37 MB
// ---------------------------------------------------------------------------
extern "C" void kernel_launch(void* const* d_in, const int* in_sizes, int n_in,
                              void* d_out, int out_size, void* d_ws, size_t ws_size,
                              hipStream_t stream) {
    const float* x  = (const float*)d_in[0];
    const float* Wq = (const float*)d_in[1];
    const float* Wk = (const float*)d_in[2];
    const float* Wv = (const float*)d_in[3];
    const float* Wo = (const float*)d_in[4];
    float* out = (float*)d_out;

    const size_t SD = (size_t)S_LEN * D_DIM;
    float* ws    = (float*)d_ws;
    float* Qb    = ws;                                    // later: Obn (bf16)
    float* Kb    = Qb + SD;
    unsigned short* Vbf = (unsigned short*)(Kb + SD);     // [2048][512] bf16
    float* ck    = (float*)(Vbf + SD);
    float* lpart = ck + (size_t)C_NUM * D_DIM;
    int*   curb  = (int*)(lpart + (size_t)TOPK * H_NUM * S_LEN);
    unsigned short* qlst = (unsigned short*)(curb + 256);
    float* Opart = (float*)(qlst + (size_t)256 * QCAP);
    unsigned short* xbf = (unsigned short*)(Opart + (size_t)TOPK * H_NUM * S_LEN * HD);
    unsigned short* Qbf = xbf + SD;
    unsigned short* Kbf = Qbf + SD;
    unsigned short* Obn = (unsigned short*)Qb;

    dim3 qkgrid(D_DIM / BN, S_LEN / BM, 2);      // Q,K fp32 + bf16 copies
    gemm_qkv<<<qkgrid, 256, 0, stream>>>(x, Wq, Wk, Qb, Kb, Qbf, Kbf, xbf);

    // V bf16 MFMA 64x32 tiles (A = xbf) + cur zeroing + chunk_keys (bx==16)
    dim3 vgrid(D_DIM / 32 + 1, S_LEN / 64);      // 17 x 32 = 544 blocks
    gemm_v<<<vgrid, 256, 0, stream>>>(xbf, Wv, Vbf, curb, Kb, ck);

    dim3 rgrid(S_LEN / 64, H_NUM);               // 32 x 8 = 256 blocks
    sims_topk<<<rgrid, 256, 0, stream>>>(Qb, ck, curb, qlst);

    dim3 agrid(ABLK, H_NUM * C_NUM);             // persistent K/V, 4 blk/hc
    moc_attn8<<<agrid, 256, 0, stream>>>(Qbf, Kbf, Vbf, curb, qlst, lpart, Opart);

    reduce_norm<<<(int)(SD / 4 / 256), 256, 0, stream>>>((const float4*)Opart, lpart, Obn);

    dim3 ogrid(D_DIM / 32, S_LEN / 64);          // 16 x 32 = 512 blocks
    gemm_out<<<ogrid, 256, 0, stream>>>(Obn, Wo, out);
}